// Round 3
// baseline (785.833 us; speedup 1.0000x reference)
//
#include <hip/hip_runtime.h>

// Problem constants (fixed by the reference):
//   B=4, NV=100000, F=200000, D=64
#define BB    4
#define NVV   100000
#define FFC   200000
#define DD    64
#define TOTV  (BB * NVV)          // 400000 vertices
#define TOTF  (BB * FFC)          // 800000 faces
#define TOTE  (TOTF * 6)          // 4800000 adjacency entries
#define NB_SCAN ((TOTV + 1023) / 1024)   // 391 scan blocks (256 thr x int4)

// ---------------------------------------------------------------------------
// CSR-build + gather path (no float atomics)
// ---------------------------------------------------------------------------

// Phase 1: per-face degree count. Each face adds 2 adjacency entries per vertex.
__global__ __launch_bounds__(256) void ul_count(
    const int* __restrict__ faces, int* __restrict__ cnt)
{
    int t = blockIdx.x * blockDim.x + threadIdx.x;
    if (t >= TOTF) return;
    int off = (t / FFC) * NVV;
    const int* fp = faces + (size_t)t * 3;
    atomicAdd(&cnt[fp[0] + off], 2);
    atomicAdd(&cnt[fp[1] + off], 2);
    atomicAdd(&cnt[fp[2] + off], 2);
}

// Phase 2a: per-block exclusive scan (256 threads x int4 = 1024 items/block).
__global__ __launch_bounds__(256) void ul_scan1(
    const int* __restrict__ cnt, int* __restrict__ rowptr, int* __restrict__ bsum)
{
    __shared__ int s[256];
    int blk = blockIdx.x, t = threadIdx.x;
    int base = blk * 1024 + t * 4;
    int4 x = make_int4(0, 0, 0, 0);
    if (base + 3 < TOTV) x = *(const int4*)(cnt + base);
    else if (base < TOTV) {
        x.x = cnt[base];
        if (base + 1 < TOTV) x.y = cnt[base + 1];
        if (base + 2 < TOTV) x.z = cnt[base + 2];
    }
    int ts = x.x + x.y + x.z + x.w;
    s[t] = ts;
    __syncthreads();
    for (int o = 1; o < 256; o <<= 1) {
        int v = (t >= o) ? s[t - o] : 0;
        __syncthreads();
        s[t] += v;
        __syncthreads();
    }
    int ex = s[t] - ts;                   // exclusive offset within block
    int4 r;
    r.x = ex;
    r.y = ex + x.x;
    r.z = ex + x.x + x.y;
    r.w = ex + x.x + x.y + x.z;
    if (base + 3 < TOTV) *(int4*)(rowptr + base) = r;
    else if (base < TOTV) {
        rowptr[base] = r.x;
        if (base + 1 < TOTV) rowptr[base + 1] = r.y;
        if (base + 2 < TOTV) rowptr[base + 2] = r.z;
    }
    if (t == 255) bsum[blk] = s[255];
}

// Phase 2b: scan the 391 block sums (single block of 512).
__global__ __launch_bounds__(512) void ul_scan2(
    const int* __restrict__ bsum, int* __restrict__ boff)
{
    __shared__ int s[512];
    int t = threadIdx.x;
    int v = (t < NB_SCAN) ? bsum[t] : 0;
    s[t] = v;
    __syncthreads();
    for (int o = 1; o < 512; o <<= 1) {
        int w = (t >= o) ? s[t - o] : 0;
        __syncthreads();
        s[t] += w;
        __syncthreads();
    }
    if (t < NB_SCAN) boff[t] = s[t] - v;  // exclusive
}

// Phase 2c: add block offsets -> rowptr is now the global exclusive scan.
__global__ __launch_bounds__(256) void ul_scan3(
    int* __restrict__ rowptr, const int* __restrict__ boff)
{
    int blk = blockIdx.x, t = threadIdx.x;
    int base = blk * 1024 + t * 4;
    int o = boff[blk];
    if (base + 3 < TOTV) {
        int4 r = *(const int4*)(rowptr + base);
        r.x += o; r.y += o; r.z += o; r.w += o;
        *(int4*)(rowptr + base) = r;
    } else if (base < TOTV) {
        rowptr[base] += o;
        if (base + 1 < TOTV) rowptr[base + 1] += o;
        if (base + 2 < TOTV) rowptr[base + 2] += o;
    }
}

// Phase 3: fill adjacency. rowptr doubles as the allocation cursor; after this
// kernel, rowptr[i] == end of vertex i's range (start = rowptr[i-1]).
__global__ __launch_bounds__(256) void ul_fill(
    const int* __restrict__ faces, int* __restrict__ rowptr, int* __restrict__ adj)
{
    int t = blockIdx.x * blockDim.x + threadIdx.x;
    if (t >= TOTF) return;
    int off = (t / FFC) * NVV;
    const int* fp = faces + (size_t)t * 3;
    int ia = fp[0] + off, ib = fp[1] + off, ic = fp[2] + off;
    int pa = atomicAdd(&rowptr[ia], 2); adj[pa] = ib; adj[pa + 1] = ic;
    int pb = atomicAdd(&rowptr[ib], 2); adj[pb] = ia; adj[pb + 1] = ic;
    int pc = atomicAdd(&rowptr[ic], 2); adj[pc] = ia; adj[pc + 1] = ib;
}

// Phase 4: gather + finalize. One wave per vertex, lane = dim.
__global__ __launch_bounds__(256) void ul_gather(
    const float* __restrict__ v, const int* __restrict__ rowptr,
    const int* __restrict__ adj, float* __restrict__ out)
{
    int gid  = blockIdx.x * blockDim.x + threadIdx.x;
    int wid  = gid >> 6;
    int lane = gid & 63;
    if (wid >= TOTV) return;

    int start = (wid == 0) ? 0 : rowptr[wid - 1];
    int end   = rowptr[wid];

    float acc = 0.0f;
    for (int base = start; base < end; base += 64) {
        int n  = min(64, end - base);
        int jv = (base + lane < end) ? adj[base + lane] : 0;
        for (int m = 0; m < n; ++m) {
            int j = __shfl(jv, m);
            acc += v[(size_t)j * DD + lane];
        }
    }
    float dg = (float)(end - start);
    float vi = v[(size_t)wid * DD + lane];
    out[(size_t)wid * DD + lane] = (dg * vi - acc) / (dg + 1e-12f);
}

// ---------------------------------------------------------------------------
// Fallback path (round-2 atomic scatter) in case ws_size is tiny.
// ---------------------------------------------------------------------------
__global__ __launch_bounds__(256) void ul_scatter(
    const float* __restrict__ v, const int* __restrict__ faces,
    float* __restrict__ nbr, float* __restrict__ deg)
{
    int gid  = blockIdx.x * blockDim.x + threadIdx.x;
    int wid  = gid >> 6;
    int lane = gid & 63;
    if (wid >= TOTF) return;
    int off = (wid / FFC) * NVV;
    const int* fp = faces + (size_t)wid * 3;
    int ia = fp[0] + off, ib = fp[1] + off, ic = fp[2] + off;
    float va = v[(size_t)ia * DD + lane];
    float vb = v[(size_t)ib * DD + lane];
    float vc = v[(size_t)ic * DD + lane];
    atomicAdd(&nbr[(size_t)ia * DD + lane], vb + vc);
    atomicAdd(&nbr[(size_t)ib * DD + lane], va + vc);
    atomicAdd(&nbr[(size_t)ic * DD + lane], va + vb);
    if (lane < 3) {
        int t = (lane == 0) ? ia : ((lane == 1) ? ib : ic);
        atomicAdd(&deg[t], 2.0f);
    }
}

__global__ __launch_bounds__(256) void ul_finalize(
    const float4* __restrict__ v4, const float* __restrict__ deg,
    float4* __restrict__ out4, int n4)
{
    int i = blockIdx.x * blockDim.x + threadIdx.x;
    if (i >= n4) return;
    float d = deg[i >> 4];
    float4 vv = v4[i];
    float4 nb = out4[i];
    float inv = 1.0f / (d + 1e-12f);
    float4 r;
    r.x = (d * vv.x - nb.x) * inv;
    r.y = (d * vv.y - nb.y) * inv;
    r.z = (d * vv.z - nb.z) * inv;
    r.w = (d * vv.w - nb.w) * inv;
    out4[i] = r;
}

// ---------------------------------------------------------------------------

extern "C" void kernel_launch(void* const* d_in, const int* in_sizes, int n_in,
                              void* d_out, int out_size, void* d_ws, size_t ws_size,
                              hipStream_t stream)
{
    const float* verts = (const float*)d_in[0];
    const int*   faces = (const int*)d_in[1];
    float*       out   = (float*)d_out;

    // Workspace layout (ints), 256B-aligned sections:
    //   cnt   [TOTV]
    //   rowptr[TOTV]      (scan result, then consumed as cursor by fill)
    //   bsum  [512]
    //   boff  [512]
    //   adj   [TOTE]
    size_t o_cnt    = 0;
    size_t o_rowptr = o_cnt    + ((size_t)TOTV * 4 + 255) / 256 * 256;
    size_t o_bsum   = o_rowptr + ((size_t)TOTV * 4 + 255) / 256 * 256;
    size_t o_boff   = o_bsum   + 512 * 4;
    size_t o_adj    = o_boff   + 512 * 4;
    size_t needed   = o_adj + (size_t)TOTE * 4;

    if (ws_size >= needed) {
        int* cnt    = (int*)((char*)d_ws + o_cnt);
        int* rowptr = (int*)((char*)d_ws + o_rowptr);
        int* bsum   = (int*)((char*)d_ws + o_bsum);
        int* boff   = (int*)((char*)d_ws + o_boff);
        int* adj    = (int*)((char*)d_ws + o_adj);

        hipMemsetAsync(cnt, 0, (size_t)TOTV * 4, stream);

        ul_count<<<(TOTF + 255) / 256, 256, 0, stream>>>(faces, cnt);
        ul_scan1<<<NB_SCAN, 256, 0, stream>>>(cnt, rowptr, bsum);
        ul_scan2<<<1, 512, 0, stream>>>(bsum, boff);
        ul_scan3<<<NB_SCAN, 256, 0, stream>>>(rowptr, boff);
        ul_fill <<<(TOTF + 255) / 256, 256, 0, stream>>>(faces, rowptr, adj);

        long long thr = (long long)TOTV * 64;
        ul_gather<<<(int)((thr + 255) / 256), 256, 0, stream>>>(verts, rowptr, adj, out);
    } else {
        // Fallback: float-atomic scatter (round-2 path).
        float* deg = (float*)d_ws;
        hipMemsetAsync(d_out, 0, (size_t)out_size * sizeof(float), stream);
        hipMemsetAsync(deg,   0, (size_t)TOTV * sizeof(float), stream);
        long long thr = (long long)TOTF * 64;
        ul_scatter<<<(int)((thr + 255) / 256), 256, 0, stream>>>(verts, faces, out, deg);
        int n4 = out_size / 4;
        ul_finalize<<<(n4 + 255) / 256, 256, 0, stream>>>(
            (const float4*)verts, deg, (float4*)out, n4);
    }
}

// Round 7
// 609.234 us; speedup vs baseline: 1.2899x; 1.2899x over previous
//
#include <hip/hip_runtime.h>

// Problem constants (fixed by the reference):
//   B=4, NV=100000, F=200000, D=64
#define BB    4
#define NVV   100000
#define FFC   200000
#define DD    64
#define TOTV  (BB * NVV)          // 400000 vertices
#define TOTF  (BB * FFC)          // 800000 faces
#define TOTE  (TOTF * 6)          // 4800000 adjacency entries
#define NB_SCAN ((TOTV + 1023) / 1024)   // 391 scan blocks (256 thr x int4)

// ---------------------------------------------------------------------------
// CSR-build + gather path (no float atomics)
// ---------------------------------------------------------------------------

// Phase 1: per-face degree count. Each face adds 2 adjacency entries per vertex.
__global__ __launch_bounds__(256) void ul_count(
    const int* __restrict__ faces, int* __restrict__ cnt)
{
    int t = blockIdx.x * blockDim.x + threadIdx.x;
    if (t >= TOTF) return;
    int off = (t / FFC) * NVV;
    const int* fp = faces + (size_t)t * 3;
    atomicAdd(&cnt[fp[0] + off], 2);
    atomicAdd(&cnt[fp[1] + off], 2);
    atomicAdd(&cnt[fp[2] + off], 2);
}

// Phase 2a: per-block exclusive scan (256 threads x int4 = 1024 items/block).
__global__ __launch_bounds__(256) void ul_scan1(
    const int* __restrict__ cnt, int* __restrict__ rowptr, int* __restrict__ bsum)
{
    __shared__ int s[256];
    int blk = blockIdx.x, t = threadIdx.x;
    int base = blk * 1024 + t * 4;
    int4 x = make_int4(0, 0, 0, 0);
    if (base + 3 < TOTV) x = *(const int4*)(cnt + base);
    else if (base < TOTV) {
        x.x = cnt[base];
        if (base + 1 < TOTV) x.y = cnt[base + 1];
        if (base + 2 < TOTV) x.z = cnt[base + 2];
    }
    int ts = x.x + x.y + x.z + x.w;
    s[t] = ts;
    __syncthreads();
    for (int o = 1; o < 256; o <<= 1) {
        int v = (t >= o) ? s[t - o] : 0;
        __syncthreads();
        s[t] += v;
        __syncthreads();
    }
    int ex = s[t] - ts;                   // exclusive offset within block
    int4 r;
    r.x = ex;
    r.y = ex + x.x;
    r.z = ex + x.x + x.y;
    r.w = ex + x.x + x.y + x.z;
    if (base + 3 < TOTV) *(int4*)(rowptr + base) = r;
    else if (base < TOTV) {
        rowptr[base] = r.x;
        if (base + 1 < TOTV) rowptr[base + 1] = r.y;
        if (base + 2 < TOTV) rowptr[base + 2] = r.z;
    }
    if (t == 255) bsum[blk] = s[255];
}

// Phase 2b: scan the 391 block sums (single block of 512).
__global__ __launch_bounds__(512) void ul_scan2(
    const int* __restrict__ bsum, int* __restrict__ boff)
{
    __shared__ int s[512];
    int t = threadIdx.x;
    int v = (t < NB_SCAN) ? bsum[t] : 0;
    s[t] = v;
    __syncthreads();
    for (int o = 1; o < 512; o <<= 1) {
        int w = (t >= o) ? s[t - o] : 0;
        __syncthreads();
        s[t] += w;
        __syncthreads();
    }
    if (t < NB_SCAN) boff[t] = s[t] - v;  // exclusive
}

// Phase 2c: add block offsets -> rowptr is now the global exclusive scan.
__global__ __launch_bounds__(256) void ul_scan3(
    int* __restrict__ rowptr, const int* __restrict__ boff)
{
    int blk = blockIdx.x, t = threadIdx.x;
    int base = blk * 1024 + t * 4;
    int o = boff[blk];
    if (base + 3 < TOTV) {
        int4 r = *(const int4*)(rowptr + base);
        r.x += o; r.y += o; r.z += o; r.w += o;
        *(int4*)(rowptr + base) = r;
    } else if (base < TOTV) {
        rowptr[base] += o;
        if (base + 1 < TOTV) rowptr[base + 1] += o;
        if (base + 2 < TOTV) rowptr[base + 2] += o;
    }
}

// Phase 3: fill adjacency. rowptr doubles as the allocation cursor; after this
// kernel, rowptr[i] == end of vertex i's range (start = rowptr[i-1]).
// All offsets are even (counts are multiples of 2) -> int2 stores are 8B-aligned.
__global__ __launch_bounds__(256) void ul_fill(
    const int* __restrict__ faces, int* __restrict__ rowptr, int* __restrict__ adj)
{
    int t = blockIdx.x * blockDim.x + threadIdx.x;
    if (t >= TOTF) return;
    int off = (t / FFC) * NVV;
    const int* fp = faces + (size_t)t * 3;
    int ia = fp[0] + off, ib = fp[1] + off, ic = fp[2] + off;
    int pa = atomicAdd(&rowptr[ia], 2); *(int2*)(adj + pa) = make_int2(ib, ic);
    int pb = atomicAdd(&rowptr[ib], 2); *(int2*)(adj + pb) = make_int2(ia, ic);
    int pc = atomicAdd(&rowptr[ic], 2); *(int2*)(adj + pc) = make_int2(ia, ib);
}

// Phase 4: gather + finalize. One wave per vertex, lane = dim.
// Unrolled 8+4+tail so up to 8 neighbor-row loads are in flight per wave
// (round 3 showed this kernel latency-bound: 1 row in flight, VALUBusy 25%).
__global__ __launch_bounds__(256) void ul_gather(
    const float* __restrict__ v, const int* __restrict__ rowptr,
    const int* __restrict__ adj, float* __restrict__ out)
{
    int gid  = blockIdx.x * blockDim.x + threadIdx.x;
    int wid  = gid >> 6;
    int lane = gid & 63;
    if (wid >= TOTV) return;

    int start = (wid == 0) ? 0 : rowptr[wid - 1];
    int end   = rowptr[wid];
    float vi  = v[(size_t)wid * DD + lane];   // independent load, adds MLP

    float acc = 0.0f;
    for (int base = start; base < end; base += 64) {
        int n  = min(64, end - base);
        int jv = (base + lane < end) ? adj[base + lane] : 0;
        int m = 0;
        for (; m + 8 <= n; m += 8) {
            int j0 = __shfl(jv, m);
            int j1 = __shfl(jv, m + 1);
            int j2 = __shfl(jv, m + 2);
            int j3 = __shfl(jv, m + 3);
            int j4 = __shfl(jv, m + 4);
            int j5 = __shfl(jv, m + 5);
            int j6 = __shfl(jv, m + 6);
            int j7 = __shfl(jv, m + 7);
            float a0 = v[(size_t)j0 * DD + lane];
            float a1 = v[(size_t)j1 * DD + lane];
            float a2 = v[(size_t)j2 * DD + lane];
            float a3 = v[(size_t)j3 * DD + lane];
            float a4 = v[(size_t)j4 * DD + lane];
            float a5 = v[(size_t)j5 * DD + lane];
            float a6 = v[(size_t)j6 * DD + lane];
            float a7 = v[(size_t)j7 * DD + lane];
            acc += ((a0 + a1) + (a2 + a3)) + ((a4 + a5) + (a6 + a7));
        }
        if (m + 4 <= n) {
            int j0 = __shfl(jv, m);
            int j1 = __shfl(jv, m + 1);
            int j2 = __shfl(jv, m + 2);
            int j3 = __shfl(jv, m + 3);
            float a0 = v[(size_t)j0 * DD + lane];
            float a1 = v[(size_t)j1 * DD + lane];
            float a2 = v[(size_t)j2 * DD + lane];
            float a3 = v[(size_t)j3 * DD + lane];
            acc += (a0 + a1) + (a2 + a3);
            m += 4;
        }
        for (; m < n; ++m) {
            int j = __shfl(jv, m);
            acc += v[(size_t)j * DD + lane];
        }
    }
    float dg = (float)(end - start);
    out[(size_t)wid * DD + lane] = (dg * vi - acc) / (dg + 1e-12f);
}

// ---------------------------------------------------------------------------
// Fallback path (round-2 atomic scatter) in case ws_size is tiny.
// ---------------------------------------------------------------------------
__global__ __launch_bounds__(256) void ul_scatter(
    const float* __restrict__ v, const int* __restrict__ faces,
    float* __restrict__ nbr, float* __restrict__ deg)
{
    int gid  = blockIdx.x * blockDim.x + threadIdx.x;
    int wid  = gid >> 6;
    int lane = gid & 63;
    if (wid >= TOTF) return;
    int off = (wid / FFC) * NVV;
    const int* fp = faces + (size_t)wid * 3;
    int ia = fp[0] + off, ib = fp[1] + off, ic = fp[2] + off;
    float va = v[(size_t)ia * DD + lane];
    float vb = v[(size_t)ib * DD + lane];
    float vc = v[(size_t)ic * DD + lane];
    atomicAdd(&nbr[(size_t)ia * DD + lane], vb + vc);
    atomicAdd(&nbr[(size_t)ib * DD + lane], va + vc);
    atomicAdd(&nbr[(size_t)ic * DD + lane], va + vb);
    if (lane < 3) {
        int t = (lane == 0) ? ia : ((lane == 1) ? ib : ic);
        atomicAdd(&deg[t], 2.0f);
    }
}

__global__ __launch_bounds__(256) void ul_finalize(
    const float4* __restrict__ v4, const float* __restrict__ deg,
    float4* __restrict__ out4, int n4)
{
    int i = blockIdx.x * blockDim.x + threadIdx.x;
    if (i >= n4) return;
    float d = deg[i >> 4];
    float4 vv = v4[i];
    float4 nb = out4[i];
    float inv = 1.0f / (d + 1e-12f);
    float4 r;
    r.x = (d * vv.x - nb.x) * inv;
    r.y = (d * vv.y - nb.y) * inv;
    r.z = (d * vv.z - nb.z) * inv;
    r.w = (d * vv.w - nb.w) * inv;
    out4[i] = r;
}

// ---------------------------------------------------------------------------

extern "C" void kernel_launch(void* const* d_in, const int* in_sizes, int n_in,
                              void* d_out, int out_size, void* d_ws, size_t ws_size,
                              hipStream_t stream)
{
    const float* verts = (const float*)d_in[0];
    const int*   faces = (const int*)d_in[1];
    float*       out   = (float*)d_out;

    // Workspace layout (ints), 256B-aligned sections:
    //   cnt   [TOTV]
    //   rowptr[TOTV]      (scan result, then consumed as cursor by fill)
    //   bsum  [512]
    //   boff  [512]
    //   adj   [TOTE]
    size_t o_cnt    = 0;
    size_t o_rowptr = o_cnt    + ((size_t)TOTV * 4 + 255) / 256 * 256;
    size_t o_bsum   = o_rowptr + ((size_t)TOTV * 4 + 255) / 256 * 256;
    size_t o_boff   = o_bsum   + 512 * 4;
    size_t o_adj    = o_boff   + 512 * 4;
    size_t needed   = o_adj + (size_t)TOTE * 4;

    if (ws_size >= needed) {
        int* cnt    = (int*)((char*)d_ws + o_cnt);
        int* rowptr = (int*)((char*)d_ws + o_rowptr);
        int* bsum   = (int*)((char*)d_ws + o_bsum);
        int* boff   = (int*)((char*)d_ws + o_boff);
        int* adj    = (int*)((char*)d_ws + o_adj);

        hipMemsetAsync(cnt, 0, (size_t)TOTV * 4, stream);

        ul_count<<<(TOTF + 255) / 256, 256, 0, stream>>>(faces, cnt);
        ul_scan1<<<NB_SCAN, 256, 0, stream>>>(cnt, rowptr, bsum);
        ul_scan2<<<1, 512, 0, stream>>>(bsum, boff);
        ul_scan3<<<NB_SCAN, 256, 0, stream>>>(rowptr, boff);
        ul_fill <<<(TOTF + 255) / 256, 256, 0, stream>>>(faces, rowptr, adj);

        long long thr = (long long)TOTV * 64;
        ul_gather<<<(int)((thr + 255) / 256), 256, 0, stream>>>(verts, rowptr, adj, out);
    } else {
        // Fallback: float-atomic scatter (round-2 path).
        float* deg = (float*)d_ws;
        hipMemsetAsync(d_out, 0, (size_t)out_size * sizeof(float), stream);
        hipMemsetAsync(deg,   0, (size_t)TOTV * sizeof(float), stream);
        long long thr = (long long)TOTF * 64;
        ul_scatter<<<(int)((thr + 255) / 256), 256, 0, stream>>>(verts, faces, out, deg);
        int n4 = out_size / 4;
        ul_finalize<<<(n4 + 255) / 256, 256, 0, stream>>>(
            (const float4*)verts, deg, (float4*)out, n4);
    }
}